// Round 2
// baseline (3675.960 us; speedup 1.0000x reference)
//
#include <hip/hip_runtime.h>
#include <math.h>

constexpr int NN = 16384;   // nodes
constexpr int NE = 65536;   // edges
constexpr int NG = 512;     // graphs

// ---------- small embed kernels ----------
__global__ void k_ee(const float* __restrict__ ea, const float* __restrict__ w,
                     const float* __restrict__ b, float* __restrict__ ee) {
    int idx = blockIdx.x * 256 + threadIdx.x;     // e*32 + j
    int e = idx >> 5, j = idx & 31;
    const float* a = ea + e * 3;
    ee[idx] = b[j] + a[0] * w[j] + a[1] * w[32 + j] + a[2] * w[64 + j];
}

__global__ void k_nh(const float* __restrict__ x, const float* __restrict__ w,
                     const float* __restrict__ b, float* __restrict__ h) {
    int idx = blockIdx.x * 256 + threadIdx.x;     // n*64 + o
    int n = idx >> 6, o = idx & 63;
    const float* xr = x + n * 9;
    float s = b[o];
#pragma unroll
    for (int a = 0; a < 9; a++) s += xr[a] * w[a * 64 + o];
    h[idx] = s;
}

__global__ void k_deg(const int* __restrict__ ei, float* __restrict__ deg) {
    int e = blockIdx.x * 256 + threadIdx.x;
    atomicAdd(&deg[ei[NE + e]], 1.0f);
}

// ew = relu(ee @ w1 + b1)   [E,32] x [32,128]
__global__ void k_ew(const float* __restrict__ ee, const float* __restrict__ w1,
                     const float* __restrict__ b1, float* __restrict__ ew) {
    int idx = blockIdx.x * 256 + threadIdx.x;     // e*128 + ko
    int e = idx >> 7, ko = idx & 127;
    const float* er = ee + e * 32;
    float s = b1[ko];
#pragma unroll 8
    for (int j = 0; j < 32; j++) s += er[j] * w1[j * 128 + ko];
    ew[idx] = fmaxf(s, 0.f);
}

// ---------- heavy fused kernel ----------
// msg_e[o] = sum_i h_src[i]*b2[i*DOUT+o] + sum_k ew[e,k] * sum_i h_src[i]*w2[k, i*DOUT+o]
// scatter-add into aggr[dst]. Block = 64 edges, 256 threads.
template <int DOUT>
__global__ __launch_bounds__(256) void k_msg(const int* __restrict__ ei,
                                             const float* __restrict__ h,
                                             const float* __restrict__ ew,
                                             const float* __restrict__ w2,
                                             const float* __restrict__ b2,
                                             float* __restrict__ aggr) {
    constexpr int OG  = DOUT / 4;    // output groups (float4 each)
    constexpr int EG  = 256 / OG;    // edge groups
    constexpr int EPT = 64 / EG;     // edges per thread
    __shared__ float h_s[64][68];    // +4 pad: e-stride 68 -> bank offset 4 per edge
    __shared__ float ew_s[64][132];
    __shared__ int src_s[64], dst_s[64];

    int t  = threadIdx.x;
    int e0 = blockIdx.x * 64;
    if (t < 64) { src_s[t] = ei[e0 + t]; dst_s[t] = ei[NE + e0 + t]; }
    __syncthreads();
    for (int idx = t; idx < 64 * 64; idx += 256) {
        int e = idx >> 6, i = idx & 63;
        h_s[e][i] = h[src_s[e] * 64 + i];
    }
    for (int idx = t; idx < 64 * 128; idx += 256) {
        int e = idx >> 7, k = idx & 127;
        ew_s[e][k] = ew[(size_t)(e0 + e) * 128 + k];
    }
    __syncthreads();

    int og = t % OG, eg = t / OG;
    int o0 = og * 4, eb = eg * EPT;

    float acc[EPT][4];
#pragma unroll
    for (int e = 0; e < EPT; e++)
#pragma unroll
        for (int j = 0; j < 4; j++) acc[e][j] = 0.f;

    // b2 (bias of per-edge weight matrix) term
    for (int i = 0; i < 64; i++) {
        float4 wv = *(const float4*)(b2 + i * DOUT + o0);
#pragma unroll
        for (int e = 0; e < EPT; e++) {
            float hv = h_s[eb + e][i];
            acc[e][0] += hv * wv.x; acc[e][1] += hv * wv.y;
            acc[e][2] += hv * wv.z; acc[e][3] += hv * wv.w;
        }
    }

    for (int k = 0; k < 128; k++) {
        float se[EPT];
#pragma unroll
        for (int e = 0; e < EPT; e++) se[e] = ew_s[eb + e][k];
        const float* w2r = w2 + (size_t)k * (64 * DOUT) + o0;
#pragma unroll 2
        for (int i = 0; i < 64; i += 4) {
            float ha[EPT][4];
#pragma unroll
            for (int e = 0; e < EPT; e++) {
                float4 hv = *(const float4*)&h_s[eb + e][i];
                ha[e][0] = hv.x; ha[e][1] = hv.y; ha[e][2] = hv.z; ha[e][3] = hv.w;
            }
#pragma unroll
            for (int ii = 0; ii < 4; ii++) {
                float4 wv = *(const float4*)(w2r + (i + ii) * DOUT);
#pragma unroll
                for (int e = 0; e < EPT; e++) {
                    float tv = se[e] * ha[e][ii];
                    acc[e][0] += tv * wv.x; acc[e][1] += tv * wv.y;
                    acc[e][2] += tv * wv.z; acc[e][3] += tv * wv.w;
                }
            }
        }
    }

#pragma unroll
    for (int e = 0; e < EPT; e++) {
        float* ap = aggr + (size_t)dst_s[eb + e] * DOUT + o0;
        atomicAdd(ap + 0, acc[e][0]); atomicAdd(ap + 1, acc[e][1]);
        atomicAdd(ap + 2, acc[e][2]); atomicAdd(ap + 3, acc[e][3]);
    }
}

// h_tmp = h @ root + aggr/deg + cb
template <int DOUT>
__global__ void k_combine(const float* __restrict__ h, const float* __restrict__ root,
                          const float* __restrict__ aggr, const float* __restrict__ deg,
                          const float* __restrict__ cb, float* __restrict__ htmp) {
    int idx = blockIdx.x * 256 + threadIdx.x;
    int n = idx / DOUT, o = idx % DOUT;
    const float* hr = h + n * 64;
    float s = cb[o] + aggr[idx] / fmaxf(deg[n], 1.f);
#pragma unroll 8
    for (int i = 0; i < 64; i++) s += hr[i] * root[i * DOUT + o];
    htmp[idx] = s;
}

// BatchNorm stats: one block per feature o
template <int DOUT>
__global__ void k_bnstats(const float* __restrict__ htmp, const float* __restrict__ g,
                          const float* __restrict__ bb, float* __restrict__ scale,
                          float* __restrict__ shift) {
    int o = blockIdx.x, t = threadIdx.x;
    float s = 0.f, q = 0.f;
    for (int n = t; n < NN; n += 256) {
        float v = htmp[n * DOUT + o];
        s += v; q += v * v;
    }
    for (int off = 32; off; off >>= 1) { s += __shfl_down(s, off); q += __shfl_down(q, off); }
    __shared__ float ls[4], lq[4];
    int w = t >> 6;
    if ((t & 63) == 0) { ls[w] = s; lq[w] = q; }
    __syncthreads();
    if (t == 0) {
        s = ls[0] + ls[1] + ls[2] + ls[3];
        q = lq[0] + lq[1] + lq[2] + lq[3];
        float mean = s / NN;
        float var  = q / NN - mean * mean;
        float sc   = g[o] * rsqrtf(var + 1e-5f);
        scale[o] = sc;
        shift[o] = bb[o] - mean * sc;
    }
}

template <int DOUT>
__global__ void k_bnapply(const float* __restrict__ htmp, const float* __restrict__ scale,
                          const float* __restrict__ shift, float* __restrict__ hout) {
    int idx = blockIdx.x * 256 + threadIdx.x;
    int o = idx & (DOUT - 1);
    hout[idx] = fmaxf(htmp[idx] * scale[o] + shift[o], 0.f);
}

__global__ void k_pool(const float* __restrict__ h, const int* __restrict__ batch,
                       float* __restrict__ pool, float* __restrict__ cnt) {
    int idx = blockIdx.x * 256 + threadIdx.x;   // n*32 + o
    int n = idx >> 5, o = idx & 31;
    int b = batch[n];
    atomicAdd(&pool[b * 32 + o], h[idx]);
    if (o == 0) atomicAdd(&cnt[b], 1.0f);
}

__global__ void k_fc(const float* __restrict__ pool, const float* __restrict__ cnt,
                     const float* __restrict__ w, const float* __restrict__ b,
                     float* __restrict__ out) {
    int idx = blockIdx.x * 256 + threadIdx.x;   // g*12 + t
    int gI = idx / 12, t = idx % 12;
    float inv = 1.f / fmaxf(cnt[gI], 1.f);
    float s = 0.f;
#pragma unroll 8
    for (int j = 0; j < 32; j++) s += pool[gI * 32 + j] * w[j * 12 + t];
    s = s * inv + b[t];
    out[idx] = 1.f / (1.f + expf(-s));
}

// ---------- launch ----------
extern "C" void kernel_launch(void* const* d_in, const int* in_sizes, int n_in,
                              void* d_out, int out_size, void* d_ws, size_t ws_size,
                              hipStream_t stream) {
    const float* x   = (const float*)d_in[0];
    const int*   ei  = (const int*)d_in[1];
    const float* ea  = (const float*)d_in[2];
    const int*   bat = (const int*)d_in[3];
    const float* eew = (const float*)d_in[4];
    const float* eeb = (const float*)d_in[5];
    const float* nw  = (const float*)d_in[6];
    const float* nb  = (const float*)d_in[7];
    const float* fcw = (const float*)d_in[32];
    const float* fcb = (const float*)d_in[33];
    float* out = (float*)d_out;

    char* ws = (char*)d_ws;
    float* ee    = (float*)(ws + 0);           // E*32*4   =  8 MB
    float* ew    = (float*)(ws + 8388608);     // E*128*4  = 32 MB
    float* hA    = (float*)(ws + 41943040);    // N*64*4
    float* hB    = (float*)(ws + 46137344);    // N*64*4
    float* htmp  = (float*)(ws + 50331648);    // N*64*4
    float* aggr  = (float*)(ws + 54525952);    // N*64*4
    float* deg   = (float*)(ws + 58720256);    // N*4
    float* scale = (float*)(ws + 58785792);    // 64*4
    float* shift = (float*)(ws + 58786048);    // 64*4
    float* pool  = (float*)(ws + 58786304);    // G*32*4
    float* cnt   = (float*)(ws + 58851840);    // G*4      (end ~58.85 MB)

    hipMemsetAsync(deg, 0, NN * 4, stream);
    hipMemsetAsync(pool, 0, NG * 32 * 4 + NG * 4, stream);  // pool + cnt contiguous

    k_ee<<<NE * 32 / 256, 256, 0, stream>>>(ea, eew, eeb, ee);
    k_nh<<<NN * 64 / 256, 256, 0, stream>>>(x, nw, nb, hA);
    k_deg<<<NE / 256, 256, 0, stream>>>(ei, deg);

    float* hin = hA;
    float* hout = hB;
    for (int L = 0; L < 3; L++) {
        const float* w1 = (const float*)d_in[8 + 8 * L + 0];
        const float* b1 = (const float*)d_in[8 + 8 * L + 1];
        const float* w2 = (const float*)d_in[8 + 8 * L + 2];
        const float* b2 = (const float*)d_in[8 + 8 * L + 3];
        const float* rt = (const float*)d_in[8 + 8 * L + 4];
        const float* cb = (const float*)d_in[8 + 8 * L + 5];
        const float* bg = (const float*)d_in[8 + 8 * L + 6];
        const float* bb = (const float*)d_in[8 + 8 * L + 7];

        hipMemsetAsync(aggr, 0, NN * 64 * 4, stream);
        k_ew<<<NE * 128 / 256, 256, 0, stream>>>(ee, w1, b1, ew);

        if (L < 2) {
            k_msg<64><<<NE / 64, 256, 0, stream>>>(ei, hin, ew, w2, b2, aggr);
            k_combine<64><<<NN * 64 / 256, 256, 0, stream>>>(hin, rt, aggr, deg, cb, htmp);
            k_bnstats<64><<<64, 256, 0, stream>>>(htmp, bg, bb, scale, shift);
            k_bnapply<64><<<NN * 64 / 256, 256, 0, stream>>>(htmp, scale, shift, hout);
        } else {
            k_msg<32><<<NE / 64, 256, 0, stream>>>(ei, hin, ew, w2, b2, aggr);
            k_combine<32><<<NN * 32 / 256, 256, 0, stream>>>(hin, rt, aggr, deg, cb, htmp);
            k_bnstats<32><<<32, 256, 0, stream>>>(htmp, bg, bb, scale, shift);
            k_bnapply<32><<<NN * 32 / 256, 256, 0, stream>>>(htmp, scale, shift, hout);
        }
        float* tmp = hin; hin = hout; hout = tmp;
    }
    // after 3 swaps: final h (32 cols) lives in hin (== hB)
    k_pool<<<NN * 32 / 256, 256, 0, stream>>>(hin, bat, pool, cnt);
    k_fc<<<NG * 12 / 256, 256, 0, stream>>>(pool, cnt, fcw, fcb, out);
}

// Round 3
// 646.252 us; speedup vs baseline: 5.6881x; 5.6881x over previous
//
#include <hip/hip_runtime.h>
#include <math.h>

constexpr int NN = 16384;   // nodes
constexpr int NE = 65536;   // edges
constexpr int NG = 512;     // graphs

typedef __attribute__((ext_vector_type(8)))  short short8;
typedef __attribute__((ext_vector_type(16))) float f32x16;

__device__ __forceinline__ short f2bf(float f) {          // f32 -> bf16 (RNE)
    unsigned u = __builtin_bit_cast(unsigned, f);
    return (short)((u + 0x7FFFu + ((u >> 16) & 1u)) >> 16);
}
__device__ __forceinline__ float b2f(unsigned short s) {  // bf16 -> f32
    return __builtin_bit_cast(float, (unsigned)s << 16);
}
__device__ __forceinline__ void gload_lds16(const unsigned short* g, unsigned short* l) {
    __builtin_amdgcn_global_load_lds(
        (const __attribute__((address_space(1))) unsigned int*)g,
        (__attribute__((address_space(3))) unsigned int*)l, 16, 0, 0);
}

// ---------- node embedding: h = x @ ne_w + ne_b ----------
__global__ void k_nh(const float* __restrict__ x, const float* __restrict__ w,
                     const float* __restrict__ b, float* __restrict__ h) {
    int idx = blockIdx.x * 256 + threadIdx.x;     // n*64 + o
    int n = idx >> 6, o = idx & 63;
    const float* xr = x + n * 9;
    float s = b[o];
#pragma unroll
    for (int a = 0; a < 9; a++) s += xr[a] * w[a * 64 + o];
    h[idx] = s;
}

__global__ void k_deg(const int* __restrict__ ei, float* __restrict__ deg) {
    int e = blockIdx.x * 256 + threadIdx.x;
    atomicAdd(&deg[ei[NE + e]], 1.0f);
}

// ---------- h (f32) -> bf16 ----------
__global__ void k_h2bf16(const float* __restrict__ h, unsigned short* __restrict__ hbf) {
    int idx = blockIdx.x * 256 + threadIdx.x;     // covers N*64/4
    float4 v = *(const float4*)(h + idx * 4);
    unsigned short o0 = (unsigned short)f2bf(v.x);
    unsigned short o1 = (unsigned short)f2bf(v.y);
    unsigned short o2 = (unsigned short)f2bf(v.z);
    unsigned short o3 = (unsigned short)f2bf(v.w);
    unsigned short* p = hbf + idx * 4;
    p[0] = o0; p[1] = o1; p[2] = o2; p[3] = o3;
}

// ---------- fused edge MLP hidden, transposed bf16 output ----------
// ewT[ko][e] = relu( (ea[e] @ ee_w + ee_b) @ w1 + b1 )[ko]
__global__ __launch_bounds__(256) void k_ewt(const float* __restrict__ ea,
                                             const float* __restrict__ eew,
                                             const float* __restrict__ eeb,
                                             const float* __restrict__ w1,
                                             const float* __restrict__ b1,
                                             unsigned short* __restrict__ ewT) {
    __shared__ float w1s[32 * 128];
    __shared__ float b1s[128];
    __shared__ float eews[96], eebs[32];
    int t = threadIdx.x;
    for (int c = t; c < 4096; c += 256) w1s[c] = w1[c];
    if (t < 128) b1s[t] = b1[t];
    if (t < 96)  eews[t] = eew[t];
    if (t < 32)  eebs[t] = eeb[t];
    __syncthreads();

    int e = blockIdx.x * 64 + (t & 63);
    int w = t >> 6;                                // wave -> ko quarter
    float a0 = ea[e * 3], a1 = ea[e * 3 + 1], a2 = ea[e * 3 + 2];
    float eer[32];
#pragma unroll
    for (int j = 0; j < 32; j++)
        eer[j] = eebs[j] + a0 * eews[j] + a1 * eews[32 + j] + a2 * eews[64 + j];
    float acc[32];
#pragma unroll
    for (int c = 0; c < 32; c++) acc[c] = b1s[w * 32 + c];
    for (int j = 0; j < 32; j++) {
        float ej = eer[j];
#pragma unroll
        for (int c = 0; c < 32; c++) acc[c] += ej * w1s[j * 128 + w * 32 + c];
    }
#pragma unroll
    for (int c = 0; c < 32; c++) {
        float v = fmaxf(acc[c], 0.f);
        ewT[(size_t)(w * 32 + c) * NE + e] = (unsigned short)f2bf(v);
    }
}

// ---------- pack w2 (+ b2 as slice kc=128) into MFMA B-fragment order ----------
// w2p[kc][s][t][lane][j] = w2[kc, (s*16 + (lane>>5)*8 + j)*DOUT + t*32 + (lane&31)]
template <int DOUT>
__global__ void k_packw2(const float* __restrict__ w2, const float* __restrict__ b2,
                         unsigned short* __restrict__ w2p) {
    constexpr int TILES = DOUT / 32;
    int idx = blockIdx.x * 256 + threadIdx.x;
    int j = idx & 7, l = (idx >> 3) & 63;
    int rest = idx >> 9;
    int tt = rest % TILES;
    int s  = (rest / TILES) & 3;
    int kc = rest / (4 * TILES);
    int i = s * 16 + (l >> 5) * 8 + j;
    int o = tt * 32 + (l & 31);
    float v = (kc < 128) ? w2[(size_t)kc * 64 * DOUT + i * DOUT + o] : b2[i * DOUT + o];
    w2p[idx] = (unsigned short)f2bf(v);
}

// ---------- the heavy kernel: per-edge matvec via MFMA + scatter-add ----------
// Block: 256 thr = 4 waves, 128 edges (32/wave). K = 129 slices (128 ew + bias).
template <int DOUT>
__global__ __launch_bounds__(256) void k_msg_mfma(const int* __restrict__ ei,
                                                  const unsigned short* __restrict__ hbf,
                                                  const unsigned short* __restrict__ ewT,
                                                  const unsigned short* __restrict__ w2p,
                                                  float* __restrict__ aggr) {
    constexpr int TILES = DOUT / 32;
    constexpr int SL = 4 * TILES * 64 * 8;          // ushorts per k-slice
    __shared__ __align__(16) unsigned short w2s[2 * SL];

    int t = threadIdx.x;
    int w = t >> 6, l = t & 63;
    int e0 = blockIdx.x * 128;
    int er = w * 32 + (l & 31);                     // edge row within block
    int hi = l >> 5;

    // hoist h[src] into registers (32 f32): i = s*16 + hi*8 + j
    int sidx = ei[e0 + er];
    const unsigned short* hrow = hbf + (size_t)sidx * 64;
    float hf[4][8];
#pragma unroll
    for (int s = 0; s < 4; s++) {
        int ib = s * 2 + hi;
        short8 hv = *(const short8*)(hrow + ib * 8);
#pragma unroll
        for (int j = 0; j < 8; j++) hf[s][j] = b2f((unsigned short)hv[j]);
    }

    // stage slice 0
    {
        const unsigned short* gsrc = w2p + (size_t)t * 8;
        unsigned short* ldst = w2s + (size_t)t * 8;
        gload_lds16(gsrc, ldst);
        if constexpr (TILES == 2) gload_lds16(gsrc + 2048, ldst + 2048);
    }
    float ewn = b2f(ewT[e0 + er]);                  // kc = 0

    f32x16 acc[TILES];
#pragma unroll
    for (int tt = 0; tt < TILES; tt++)
#pragma unroll
        for (int r = 0; r < 16; r++) acc[tt][r] = 0.f;

    __syncthreads();                                 // drains stage(0)

    for (int kc = 0; kc < 129; kc++) {
        float ewc = ewn;
        if (kc + 1 < 129) {                          // prefetch next slice
            const unsigned short* gsrc = w2p + (size_t)(kc + 1) * SL + t * 8;
            unsigned short* ldst = w2s + (size_t)((kc + 1) & 1) * SL + t * 8;
            gload_lds16(gsrc, ldst);
            if constexpr (TILES == 2) gload_lds16(gsrc + 2048, ldst + 2048);
        }
        ewn = (kc + 1 < 128) ? b2f(ewT[(size_t)(kc + 1) * NE + e0 + er]) : 1.0f;

        const unsigned short* buf = w2s + (size_t)(kc & 1) * SL;
#pragma unroll
        for (int s = 0; s < 4; s++) {
            short8 a;
#pragma unroll
            for (int j = 0; j < 8; j++) a[j] = f2bf(hf[s][j] * ewc);
#pragma unroll
            for (int tt = 0; tt < TILES; tt++) {
                short8 b = *(const short8*)(buf + ((s * TILES + tt) * 64 + l) * 8);
                acc[tt] = __builtin_amdgcn_mfma_f32_32x32x16_bf16(a, b, acc[tt], 0, 0, 0);
            }
        }
        __syncthreads();                             // drain stage(kc+1) + buffer handoff
    }

    // epilogue: scatter-add. D: col = l&31, row = (r&3) + 8*(r>>2) + 4*hi
    int ebase = e0 + w * 32;
#pragma unroll
    for (int r = 0; r < 16; r++) {
        int row = (r & 3) + 8 * (r >> 2) + 4 * hi;
        int d = ei[NE + ebase + row];
#pragma unroll
        for (int tt = 0; tt < TILES; tt++)
            atomicAdd(&aggr[(size_t)d * DOUT + tt * 32 + (l & 31)], acc[tt][r]);
    }
}

// ---------- combine: h @ root + aggr/deg + cb ----------
template <int DOUT>
__global__ void k_combine(const float* __restrict__ h, const float* __restrict__ root,
                          const float* __restrict__ aggr, const float* __restrict__ deg,
                          const float* __restrict__ cb, float* __restrict__ htmp) {
    int idx = blockIdx.x * 256 + threadIdx.x;
    int n = idx / DOUT, o = idx % DOUT;
    const float* hr = h + n * 64;
    float s = cb[o] + aggr[idx] / fmaxf(deg[n], 1.f);
#pragma unroll 8
    for (int i = 0; i < 64; i++) s += hr[i] * root[i * DOUT + o];
    htmp[idx] = s;
}

// ---------- BatchNorm ----------
template <int DOUT>
__global__ void k_bnstats(const float* __restrict__ htmp, const float* __restrict__ g,
                          const float* __restrict__ bb, float* __restrict__ scale,
                          float* __restrict__ shift) {
    int o = blockIdx.x, t = threadIdx.x;
    float s = 0.f, q = 0.f;
    for (int n = t; n < NN; n += 256) {
        float v = htmp[n * DOUT + o];
        s += v; q += v * v;
    }
    for (int off = 32; off; off >>= 1) { s += __shfl_down(s, off); q += __shfl_down(q, off); }
    __shared__ float ls[4], lq[4];
    int w = t >> 6;
    if ((t & 63) == 0) { ls[w] = s; lq[w] = q; }
    __syncthreads();
    if (t == 0) {
        s = ls[0] + ls[1] + ls[2] + ls[3];
        q = lq[0] + lq[1] + lq[2] + lq[3];
        float mean = s / NN;
        float var  = q / NN - mean * mean;
        float sc   = g[o] * rsqrtf(var + 1e-5f);
        scale[o] = sc;
        shift[o] = bb[o] - mean * sc;
    }
}

template <int DOUT>
__global__ void k_bnapply(const float* __restrict__ htmp, const float* __restrict__ scale,
                          const float* __restrict__ shift, float* __restrict__ hout) {
    int idx = blockIdx.x * 256 + threadIdx.x;
    int o = idx & (DOUT - 1);
    hout[idx] = fmaxf(htmp[idx] * scale[o] + shift[o], 0.f);
}

// ---------- pool + fc ----------
__global__ void k_pool(const float* __restrict__ h, const int* __restrict__ batch,
                       float* __restrict__ pool, float* __restrict__ cnt) {
    int idx = blockIdx.x * 256 + threadIdx.x;   // n*32 + o
    int n = idx >> 5, o = idx & 31;
    int b = batch[n];
    atomicAdd(&pool[b * 32 + o], h[idx]);
    if (o == 0) atomicAdd(&cnt[b], 1.0f);
}

__global__ void k_fc(const float* __restrict__ pool, const float* __restrict__ cnt,
                     const float* __restrict__ w, const float* __restrict__ b,
                     float* __restrict__ out) {
    int idx = blockIdx.x * 256 + threadIdx.x;   // g*12 + t
    int gI = idx / 12, t = idx % 12;
    float inv = 1.f / fmaxf(cnt[gI], 1.f);
    float s = 0.f;
#pragma unroll 8
    for (int j = 0; j < 32; j++) s += pool[gI * 32 + j] * w[j * 12 + t];
    s = s * inv + b[t];
    out[idx] = 1.f / (1.f + expf(-s));
}

// ---------- launch ----------
extern "C" void kernel_launch(void* const* d_in, const int* in_sizes, int n_in,
                              void* d_out, int out_size, void* d_ws, size_t ws_size,
                              hipStream_t stream) {
    const float* x   = (const float*)d_in[0];
    const int*   ei  = (const int*)d_in[1];
    const float* ea  = (const float*)d_in[2];
    const int*   bat = (const int*)d_in[3];
    const float* eew = (const float*)d_in[4];
    const float* eeb = (const float*)d_in[5];
    const float* nw  = (const float*)d_in[6];
    const float* nb  = (const float*)d_in[7];
    const float* fcw = (const float*)d_in[32];
    const float* fcb = (const float*)d_in[33];
    float* out = (float*)d_out;

    char* ws = (char*)d_ws;
    unsigned short* ewT = (unsigned short*)(ws + 0);          // 128*E*2 = 16.78 MB
    unsigned short* w2p = (unsigned short*)(ws + 16777216);   // <= 1.06 MB
    float* hA    = (float*)(ws + 18874368);                   // N*64*4
    float* hB    = (float*)(ws + 23068672);
    float* htmp  = (float*)(ws + 27262976);
    float* aggr  = (float*)(ws + 31457280);
    unsigned short* hbf = (unsigned short*)(ws + 35651584);   // N*64*2
    float* deg   = (float*)(ws + 37748736);                   // N*4
    float* scale = (float*)(ws + 37814272);
    float* shift = (float*)(ws + 37814528);
    float* pool  = (float*)(ws + 37814784);                   // G*32*4
    float* cnt   = (float*)(ws + 37880320);                   // G*4

    hipMemsetAsync(deg, 0, NN * 4, stream);
    hipMemsetAsync(pool, 0, NG * 32 * 4 + NG * 4, stream);

    k_nh<<<NN * 64 / 256, 256, 0, stream>>>(x, nw, nb, hA);
    k_deg<<<NE / 256, 256, 0, stream>>>(ei, deg);

    float* hin = hA;
    float* hout = hB;
    for (int L = 0; L < 3; L++) {
        const float* w1 = (const float*)d_in[8 + 8 * L + 0];
        const float* b1 = (const float*)d_in[8 + 8 * L + 1];
        const float* w2 = (const float*)d_in[8 + 8 * L + 2];
        const float* b2 = (const float*)d_in[8 + 8 * L + 3];
        const float* rt = (const float*)d_in[8 + 8 * L + 4];
        const float* cb = (const float*)d_in[8 + 8 * L + 5];
        const float* bg = (const float*)d_in[8 + 8 * L + 6];
        const float* bb = (const float*)d_in[8 + 8 * L + 7];

        hipMemsetAsync(aggr, 0, NN * 64 * 4, stream);
        k_ewt<<<NE / 64, 256, 0, stream>>>(ea, eew, eeb, w1, b1, ewT);
        k_h2bf16<<<NN * 64 / 4 / 256, 256, 0, stream>>>(hin, hbf);

        if (L < 2) {
            k_packw2<64><<<129 * 4 * 2 * 64 * 8 / 256, 256, 0, stream>>>(w2, b2, w2p);
            k_msg_mfma<64><<<NE / 128, 256, 0, stream>>>(ei, hbf, ewT, w2p, aggr);
            k_combine<64><<<NN * 64 / 256, 256, 0, stream>>>(hin, rt, aggr, deg, cb, htmp);
            k_bnstats<64><<<64, 256, 0, stream>>>(htmp, bg, bb, scale, shift);
            k_bnapply<64><<<NN * 64 / 256, 256, 0, stream>>>(htmp, scale, shift, hout);
        } else {
            k_packw2<32><<<129 * 4 * 1 * 64 * 8 / 256, 256, 0, stream>>>(w2, b2, w2p);
            k_msg_mfma<32><<<NE / 128, 256, 0, stream>>>(ei, hbf, ewT, w2p, aggr);
            k_combine<32><<<NN * 32 / 256, 256, 0, stream>>>(hin, rt, aggr, deg, cb, htmp);
            k_bnstats<32><<<32, 256, 0, stream>>>(htmp, bg, bb, scale, shift);
            k_bnapply<32><<<NN * 32 / 256, 256, 0, stream>>>(htmp, scale, shift, hout);
        }
        float* tmp = hin; hin = hout; hout = tmp;
    }
    k_pool<<<NN * 32 / 256, 256, 0, stream>>>(hin, bat, pool, cnt);
    k_fc<<<NG * 12 / 256, 256, 0, stream>>>(pool, cnt, fcw, fcb, out);
}